// Round 17
// baseline (30.377 us; speedup 1.0000x reference)
//
#include <hip/hip_runtime.h>
#include <hip/hip_bf16.h>

#define L_CLS 2048
#define D_DIM 512
#define T_SZ  512
#define NT    511              // T-1 transitions per sequence
#define NOUT  (64 * NT)        // 32704
#define NCHUNK 16              // 128-col chunks
#define LOG2E 1.4426950408889634f
#define LN2   0.6931471805599453f
#define SHIFT 128.0f           // fixed exponent shift: sum 2^(x*log2e - SHIFT)

typedef __attribute__((ext_vector_type(8))) short bf16x8;
typedef __attribute__((ext_vector_type(4))) float f32x4;

static __device__ __forceinline__ short f2bf(float x) {
    return (short)__bfloat16_as_ushort(__float2bfloat16(x));
}
static __device__ __forceinline__ float bits2f(unsigned short u) {
    union { unsigned int i; float f; } v; v.i = ((unsigned int)u) << 16; return v.f;
}

// ---------------------------------------------------------------- conv kernel
__global__ void conv_bf16(const float* __restrict__ srcE, const float* __restrict__ tgtE,
                          __hip_bfloat16* __restrict__ Sb, __hip_bfloat16* __restrict__ Tb) {
    int i = blockIdx.x * blockDim.x + threadIdx.x;   // groups of 8
    if (i >= (L_CLS * D_DIM) / 8) return;
    const f32x4* s4 = reinterpret_cast<const f32x4*>(srcE) + i * 2;
    const f32x4* t4 = reinterpret_cast<const f32x4*>(tgtE) + i * 2;
    f32x4 s0 = s4[0], s1 = s4[1];
    f32x4 t0 = t4[0], t1 = t4[1];
    bf16x8 so, to;
#pragma unroll
    for (int j = 0; j < 4; ++j) {
        so[j] = f2bf(s0[j]); so[j + 4] = f2bf(s1[j]);
        to[j] = f2bf(t0[j]); to[j + 4] = f2bf(t1[j]);
    }
    reinterpret_cast<bf16x8*>(Sb)[i] = so;
    reinterpret_cast<bf16x8*>(Tb)[i] = to;
}

// ---------------------------------- bf16 GEMM + exp-sums (NO M, swizzled) ---
// R12 structure: grid (16,16) x 512 thr (8 waves), wave = 16 rows x 128 cols,
// reg-staged B + global prefetch under MFMAs, 2 barriers/slice. Changes:
//  - NO logit matrix writes (R15 measured 17.4 MB WRITE/iter; consumers need
//    only 131 KB -> scores recomputes those dots directly).
//  - LDS XOR swizzle (elem ^= (row&7)<<3 on write AND read): kills the
//    measured 8.4M bank-conflict cycles (16 rows same byte-offset = 16-way;
//    swizzle -> 2-way = free per m136).
__launch_bounds__(512)
__global__ void gemm_lse_bf16(const __hip_bfloat16* __restrict__ Sb,
                              const __hip_bfloat16* __restrict__ Tb,
                              float* __restrict__ psum) {
    __shared__ __hip_bfloat16 Blds[128 * 128];   // 32768 B, linear + XOR

    const int tid  = threadIdx.x;
    const int wave = tid >> 6;           // 0..7
    const int lane = tid & 63;
    const int lr   = lane & 15;
    const int hi   = lane >> 4;
    const int C    = blockIdx.x * 128;
    const int R    = blockIdx.y * 128 + wave * 16;

    f32x4 acc[8];
#pragma unroll
    for (int ct = 0; ct < 8; ++ct) acc[ct] = (f32x4){0.f, 0.f, 0.f, 0.f};

    bf16x8 stg[4], an[4];
    // prologue: slice 0 B-chunk + A-frags into regs
#pragma unroll
    for (int i = 0; i < 4; ++i) {
        int p = tid + 512 * i;           // 0..2047: row p>>4, 16B-chunk p&15
        stg[i] = *reinterpret_cast<const bf16x8*>(
            &Tb[(C + (p >> 4)) * D_DIM + (p & 15) * 8]);
    }
#pragma unroll
    for (int ks = 0; ks < 4; ++ks)
        an[ks] = *reinterpret_cast<const bf16x8*>(
            &Sb[(R + lr) * D_DIM + ks * 32 + hi * 8]);

#pragma unroll 1
    for (int s = 0; s < 4; ++s) {
        // ds_write staged B chunk, XOR-swizzled slot within each 256B row
#pragma unroll
        for (int i = 0; i < 4; ++i) {
            int p   = tid + 512 * i;
            int row = p >> 4;
            int e   = (p & 15) * 8;
            *reinterpret_cast<bf16x8*>(
                &Blds[row * 128 + (e ^ ((row & 7) << 3))]) = stg[i];
        }
        bf16x8 a[4];
#pragma unroll
        for (int ks = 0; ks < 4; ++ks) a[ks] = an[ks];
        __syncthreads();

        if (s < 3) {   // prefetch next slice under the MFMAs
#pragma unroll
            for (int i = 0; i < 4; ++i) {
                int p = tid + 512 * i;
                stg[i] = *reinterpret_cast<const bf16x8*>(
                    &Tb[(C + (p >> 4)) * D_DIM + (s + 1) * 128 + (p & 15) * 8]);
            }
#pragma unroll
            for (int ks = 0; ks < 4; ++ks)
                an[ks] = *reinterpret_cast<const bf16x8*>(
                    &Sb[(R + lr) * D_DIM + (s + 1) * 128 + ks * 32 + hi * 8]);
        }

#pragma unroll
        for (int ks = 0; ks < 4; ++ks) {
#pragma unroll
            for (int ct = 0; ct < 8; ++ct) {
                int row = ct * 16 + lr;
                int e   = (ks * 32 + hi * 8) ^ ((lr & 7) << 3);
                bf16x8 b = *reinterpret_cast<const bf16x8*>(&Blds[row * 128 + e]);
                acc[ct] = __builtin_amdgcn_mfma_f32_16x16x32_bf16(a[ks], b, acc[ct], 0, 0, 0);
            }
        }
        __syncthreads();
    }

    // ---- epilogue: fixed-shift exp sums only ----
    float p[4];
#pragma unroll
    for (int i = 0; i < 4; ++i) {
        p[i] = 0.f;
#pragma unroll
        for (int ct = 0; ct < 8; ++ct)
            p[i] += exp2f(acc[ct][i] * LOG2E - SHIFT);
    }
#pragma unroll
    for (int off = 1; off < 16; off <<= 1)
#pragma unroll
        for (int i = 0; i < 4; ++i) p[i] += __shfl_xor(p[i], off);
    if (lr == 0) {
#pragma unroll
        for (int i = 0; i < 4; ++i)
            psum[(R + hi * 4 + i) * NCHUNK + blockIdx.x] = p[i];
    }
}

// ------------------------------------------------- scores: direct bf16 dots
// one wave per output: out = dot(Sb[src], Tb[tgt]) - lse(src); lse partials
// folded into the same butterfly (lanes 0..15 carry psum entries).
__launch_bounds__(256)
__global__ void scores_dot(const int* __restrict__ labels,
                           const __hip_bfloat16* __restrict__ Sb,
                           const __hip_bfloat16* __restrict__ Tb,
                           const float* __restrict__ psum,
                           float* __restrict__ out) {
    const int wid  = blockIdx.x * 4 + (threadIdx.x >> 6);   // grid sized exactly
    const int lane = threadIdx.x & 63;
    const int b = wid / NT;
    const int t = wid - b * NT;
    const int src = labels[b * T_SZ + t];
    const int tgt = labels[b * T_SZ + t + 1];

    bf16x8 sv = *reinterpret_cast<const bf16x8*>(&Sb[src * D_DIM + lane * 8]);
    bf16x8 tv = *reinterpret_cast<const bf16x8*>(&Tb[tgt * D_DIM + lane * 8]);
    float acc = 0.f;
#pragma unroll
    for (int j = 0; j < 8; ++j)
        acc += bits2f((unsigned short)sv[j]) * bits2f((unsigned short)tv[j]);

    float ps = (lane < NCHUNK) ? psum[src * NCHUNK + lane] : 0.f;
#pragma unroll
    for (int off = 32; off; off >>= 1) {
        acc += __shfl_xor(acc, off);
        ps  += __shfl_xor(ps, off);
    }
    if (lane == 0) out[wid] = acc - (log2f(ps) + SHIFT) * LN2;
}

// ------------------------------------------------------------------- launcher
extern "C" void kernel_launch(void* const* d_in, const int* in_sizes, int n_in,
                              void* d_out, int out_size, void* d_ws, size_t ws_size,
                              hipStream_t stream) {
    const int*   labels = (const int*)d_in[0];
    const float* srcE   = (const float*)d_in[1];
    const float* tgtE   = (const float*)d_in[2];
    float*       out    = (float*)d_out;

    const size_t tbl = (size_t)L_CLS * D_DIM;
    __hip_bfloat16* Sb = (__hip_bfloat16*)d_ws;                    // 2 MB
    __hip_bfloat16* Tb = Sb + tbl;                                 // 2 MB
    float* psum = (float*)((char*)d_ws + 2 * tbl * sizeof(__hip_bfloat16)); // 128 KB

    conv_bf16<<<(int)(tbl / 8 + 255) / 256, 256, 0, stream>>>(srcE, tgtE, Sb, Tb);
    gemm_lse_bf16<<<dim3(NCHUNK, 16), 512, 0, stream>>>(Sb, Tb, psum);
    scores_dot<<<NOUT / 4, 256, 0, stream>>>(labels, Sb, Tb, psum, out);
}